// Round 15
// baseline (647.002 us; speedup 1.0000x reference)
//
#include <hip/hip_runtime.h>
#include <cmath>

typedef __attribute__((ext_vector_type(8))) _Float16 f16x8;
typedef __attribute__((ext_vector_type(2))) __fp16 fp16x2;   // cvt_pkrtz return type
typedef __attribute__((ext_vector_type(4))) float f32x4;
typedef unsigned int u32;

__device__ __forceinline__ float tanh_fast(float z) {
    // tanh(z) = 1 - 2/(exp(2z)+1), exp via hardware exp2
    float e = __builtin_amdgcn_exp2f(z * 2.8853900817779268f); // 2*log2(e)
    return 1.0f - 2.0f * __builtin_amdgcn_rcpf(e + 1.0f);
}

__device__ __forceinline__ float f4c(const float4& v, int i) {
    switch (i) { case 0: return v.x; case 1: return v.y; case 2: return v.z; default: return v.w; }
}

// f32 pair -> packed f16x2 in a u32 (RTZ; precision headroom is ample)
__device__ __forceinline__ u32 pk16(float a, float b) {
    fp16x2 hp = __builtin_amdgcn_cvt_pkrtz(a, b);
    return __builtin_bit_cast(u32, hp);
}

// ---------------------------------------------------------------------------
// Prep kernel: convert W1..W4 to f16 (RNE) in MFMA-fragment lane order.
// Layout function (same for A and B operands, HW-verified R4/R6/R8):
//   lane = ((k>>2)&3)*16 + (j&15) ;  s = ((k>>4)&1)*4 + (k&3)
//   blob short-index: (((l*8 + n)*4 + kc)*512 + lane*8 + s
//   l = 0..2 -> W1..W3 (n = j>>4, 8 tiles), l = 3 -> W4 padded to 16 cols, n=0
// ---------------------------------------------------------------------------
__global__ void prep_w_frags(const float* __restrict__ W1, const float* __restrict__ W2,
                             const float* __restrict__ W3, const float* __restrict__ W4,
                             unsigned short* __restrict__ wsf)
{
    int t = blockIdx.x * blockDim.x + threadIdx.x;   // 0 .. 65535
    int l = t >> 14;
    int rem = t & 16383;
    int k = rem >> 7;
    int j = rem & 127;
    float f;
    if (l == 0)      f = W1[k*128 + j];
    else if (l == 1) f = W2[k*128 + j];
    else if (l == 2) f = W3[k*128 + j];
    else {
        if (j >= 16) return;
        f = (j < 4) ? W4[k*4 + j] : 0.0f;
    }
    _Float16 hf = (_Float16)f;                       // RNE
    unsigned short h16 = __builtin_bit_cast(unsigned short, hf);
    int n = j >> 4, jm = j & 15;
    int kc = k >> 5, half = (k >> 4) & 1, qk = (k >> 2) & 3, e = k & 3;
    int lane = qk*16 + jm, s = half*4 + e;
    size_t idx = (((size_t)l*8 + n)*4 + kc)*512 + (size_t)lane*8 + s;
    wsf[idx] = h16;
}

// ---------------------------------------------------------------------------
// Main kernel (transposed, pure f16 single-pass): 16 points/WG, 4 waves.
// Z^T = W^T * S :  A = f16 weight fragments from wsf (global, L2-hot),
//                  B = f16 state fragments; kc==wv comes from the wave's own
//                  registers (it wrote them), kc!=wv from LDS.
// LDS 28 KB -> 5 WG/CU.
// ---------------------------------------------------------------------------
__global__ __launch_bounds__(256, 5)
void pinn_mfma_kernel(
    const float* __restrict__ gx, const float* __restrict__ gy, const float* __restrict__ gt,
    const float* __restrict__ W0, const float* __restrict__ b0,
    const float* __restrict__ b1, const float* __restrict__ b2, const float* __restrict__ b3,
    const float* __restrict__ b4,
    const unsigned short* __restrict__ wsf,
    float* __restrict__ out, int n)
{
    __shared__ uint4 Sfh[4][7][64];       // state fragments : 28672 B

    const int tid  = threadIdx.x;
    const int lane = tid & 63;
    const int wv   = tid >> 6;            // wave 0..3 -> owns kc=wv
    const int q    = lane >> 4;           // 0..3
    const int jm   = lane & 15;           // point index p
    const int gp0  = blockIdx.x * 16;

    auto wfrag = [&](int l, int mt, int kc) -> f16x8 {
        return *reinterpret_cast<const f16x8*>(
            wsf + (((size_t)l*8 + mt)*4 + kc)*512 + (size_t)lane*8);
    };

    // ---- point coords (one point per 16-lane group) ----
    int gp = gp0 + jm; if (gp >= n) gp = n - 1;
    const float xv = gx[gp], yv = gy[gp], tv = gt[gp];

    // ---- W0 rows + all biases for owned j's: j = (2wv+ms)*16 + q*4 + i ----
    const int j0a = (2*wv + 0)*16 + q*4;
    const int j0b = (2*wv + 1)*16 + q*4;
    float4 w0x[2], w0y[2], w0t[2], b0v[2], bias[3][2];
    w0x[0] = *reinterpret_cast<const float4*>(W0 + j0a);
    w0x[1] = *reinterpret_cast<const float4*>(W0 + j0b);
    w0y[0] = *reinterpret_cast<const float4*>(W0 + 128 + j0a);
    w0y[1] = *reinterpret_cast<const float4*>(W0 + 128 + j0b);
    w0t[0] = *reinterpret_cast<const float4*>(W0 + 256 + j0a);
    w0t[1] = *reinterpret_cast<const float4*>(W0 + 256 + j0b);
    b0v[0] = *reinterpret_cast<const float4*>(b0 + j0a);
    b0v[1] = *reinterpret_cast<const float4*>(b0 + j0b);
    bias[0][0] = *reinterpret_cast<const float4*>(b1 + j0a);
    bias[0][1] = *reinterpret_cast<const float4*>(b1 + j0b);
    bias[1][0] = *reinterpret_cast<const float4*>(b2 + j0a);
    bias[1][1] = *reinterpret_cast<const float4*>(b2 + j0b);
    bias[2][0] = *reinterpret_cast<const float4*>(b3 + j0a);
    bias[2][1] = *reinterpret_cast<const float4*>(b3 + j0b);

    // ---- pack-and-store helper state (packed f16 cvt) ----
    u32 hw[7][4];
    float tmp[7];
    auto pack7 = [&](int sidx, const float* o) {
        if ((sidx & 1) == 0) {
            #pragma unroll
            for (int v = 0; v < 7; ++v) tmp[v] = o[v];
        } else {
            const int d = sidx >> 1;
            #pragma unroll
            for (int v = 0; v < 7; ++v)
                hw[v][d] = pk16(tmp[v], o[v]);
        }
    };
    auto storeFrags = [&]() {
        #pragma unroll
        for (int v = 0; v < 7; ++v)
            Sfh[wv][v][lane] = make_uint4(hw[v][0], hw[v][1], hw[v][2], hw[v][3]);
    };
    auto ownFrag = [&](int v) -> f16x8 {
        return __builtin_bit_cast(f16x8, make_uint4(hw[v][0], hw[v][1], hw[v][2], hw[v][3]));
    };

    // ---- layer 0: 3 -> 128, seed value + 6 derivative vectors ----
    #pragma unroll
    for (int ms = 0; ms < 2; ++ms) {
        #pragma unroll
        for (int i = 0; i < 4; ++i) {
            const float wx = f4c(w0x[ms], i), wy = f4c(w0y[ms], i), wt = f4c(w0t[ms], i);
            float z = fmaf(xv, wx, fmaf(yv, wy, fmaf(tv, wt, f4c(b0v[ms], i))));
            float s = tanh_fast(z);
            float d = 1.0f - s*s;
            float m2sd = -2.0f * s * d;
            float o[7] = { s, d*wx, d*wy, d*wt, m2sd*wx*wx, m2sd*wy*wy, m2sd*wx*wy };
            pack7(ms*4 + i, o);
        }
    }
    storeFrags();
    __syncthreads();

    // ---- hidden layers 1..3 via MFMA (f16), transposed ----
    #pragma unroll
    for (int l = 0; l < 3; ++l) {
        // this layer's weight fragments (A-operands)
        f16x8 wf[2][4];   // [ms][kc]
        #pragma unroll
        for (int ms = 0; ms < 2; ++ms)
          #pragma unroll
          for (int kc = 0; kc < 4; ++kc)
            wf[ms][kc] = wfrag(l, 2*wv + ms, kc);

        f32x4 acc[7][2];
        #pragma unroll
        for (int v = 0; v < 7; ++v)
          #pragma unroll
          for (int ms = 0; ms < 2; ++ms)
            acc[v][ms] = (f32x4){0.f, 0.f, 0.f, 0.f};

        #pragma unroll
        for (int kc = 0; kc < 4; ++kc) {
          #pragma unroll
          for (int v = 0; v < 7; ++v) {
            f16x8 bh = (kc == wv) ? ownFrag(v)
                                  : *reinterpret_cast<const f16x8*>(&Sfh[kc][v][lane]);
            #pragma unroll
            for (int ms = 0; ms < 2; ++ms)
                acc[v][ms] = __builtin_amdgcn_mfma_f32_16x16x32_f16(wf[ms][kc], bh, acc[v][ms], 0, 0, 0);
          }
        }
        __syncthreads();   // all reads of Sfh done before overwrite

        // in-register nonlinearity + derivative propagation + repack
        #pragma unroll
        for (int ms = 0; ms < 2; ++ms) {
            #pragma unroll
            for (int i = 0; i < 4; ++i) {
                float z   = acc[0][ms][i] + f4c(bias[l][ms], i);
                float zx  = acc[1][ms][i];
                float zy  = acc[2][ms][i];
                float zt  = acc[3][ms][i];
                float zxx = acc[4][ms][i];
                float zyy = acc[5][ms][i];
                float zxy = acc[6][ms][i];
                float s = tanh_fast(z);
                float d = 1.0f - s*s;
                float m2s = -2.0f * s;
                float o[7] = { s, d*zx, d*zy, d*zt,
                               d * fmaf(m2s * zx, zx, zxx),
                               d * fmaf(m2s * zy, zy, zyy),
                               d * fmaf(m2s * zx, zy, zxy) };
                pack7(ms*4 + i, o);
            }
        }
        storeFrags();
        __syncthreads();
    }

    // ---- final layer 128 -> 4 (wave 0 only; A = W4^T padded to 16 rows) ----
    if (wv == 0) {
        f16x8 w4[4];
        #pragma unroll
        for (int kc = 0; kc < 4; ++kc)
            w4[kc] = wfrag(3, 0, kc);

        f32x4 a4[7];
        #pragma unroll
        for (int v = 0; v < 7; ++v) a4[v] = (f32x4){0.f, 0.f, 0.f, 0.f};

        #pragma unroll
        for (int kc = 0; kc < 4; ++kc)
          #pragma unroll
          for (int v = 0; v < 7; ++v) {
            f16x8 bh = (kc == 0) ? ownFrag(v)
                                 : *reinterpret_cast<const f16x8*>(&Sfh[kc][v][lane]);
            a4[v] = __builtin_amdgcn_mfma_f32_16x16x32_f16(w4[kc], bh, a4[v], 0, 0, 0);
          }

        // lanes with q==0 hold outputs o = 0..3 for point jm in a4[v][o]
        if (q == 0) {
            float r[7][4];
            #pragma unroll
            for (int v = 0; v < 7; ++v) {
                r[v][0] = a4[v][0]; r[v][1] = a4[v][1];
                r[v][2] = a4[v][2]; r[v][3] = a4[v][3];
            }
            const float u  = r[0][0] + b4[0];
            const float v  = r[0][1] + b4[1];
            const float a  = r[0][3] + b4[3];
            const float u_x = r[1][0], u_y = r[2][0], u_t = r[3][0];
            const float v_x = r[1][1], v_y = r[2][1], v_t = r[3][1];
            const float p_x = r[1][2], p_y = r[2][2];
            const float a_x = r[1][3], a_y = r[2][3], a_t = r[3][3];
            const float u_xx = r[4][0], u_yy = r[5][0];
            const float v_xx = r[4][1], v_yy = r[5][1];
            const float a_xx = r[4][3], a_yy = r[5][3], a_xy = r[6][3];

            const float MU1 = 0.001f, MU2 = 1.8e-5f;
            const float RHO1 = 1000.0f, RHO2 = 1.225f;
            const float SIGMA = 0.0728f, GACC = 9.81f;

            const float mu   = MU2 + (MU1 - MU2) * a;
            const float mu_x = (MU1 - MU2) * a_x;
            const float mu_y = (MU1 - MU2) * a_y;
            const float rho  = RHO2 + (RHO1 - RHO2) * a;

            const float abs_grad = sqrtf(a_x*a_x + a_y*a_y + 1e-12f);
            const float ag3 = abs_grad * abs_grad * abs_grad;
            const float curvature =
                -((a_xx + a_yy) / abs_grad
                  - (a_x*a_x*a_xx + a_y*a_y*a_yy + 2.0f*a_x*a_y*a_xy) / ag3);

            const float one_Re   = mu   / RHO2;
            const float one_Re_x = mu_x / RHO2;
            const float one_Re_y = mu_y / RHO2;
            const float one_We   = SIGMA / RHO2;
            const float one_Fr   = GACC;
            const float rr       = rho / RHO2;

            const float PDE_m = u_x + v_y;
            const float PDE_a = a_t + u*a_x + v*a_y;
            const float PDE_u = (u_t + u*u_x + v*u_y) * rr + p_x
                                - one_We * curvature * a_x
                                - one_Re * (u_xx + u_yy)
                                - 2.0f * one_Re_x * u_x
                                - one_Re_y * (u_y + v_x);
            const float PDE_v = (v_t + u*v_x + v*v_y) * rr + p_y
                                - one_We * curvature * a_y
                                - rr * one_Fr
                                - one_Re * (v_xx + v_yy)
                                - 2.0f * one_Re_y * v_y
                                - one_Re_x * (u_y + v_x);

            if (gp0 + jm < n) {
                float4 res; res.x = PDE_m; res.y = PDE_u; res.z = PDE_v; res.w = PDE_a;
                *reinterpret_cast<float4*>(out + (size_t)(gp0 + jm) * 4) = res;
            }
        }
    }
}

extern "C" void kernel_launch(void* const* d_in, const int* in_sizes, int n_in,
                              void* d_out, int out_size, void* d_ws, size_t ws_size,
                              hipStream_t stream)
{
    const float* x  = (const float*)d_in[0];
    const float* y  = (const float*)d_in[1];
    const float* t  = (const float*)d_in[2];
    const float* W0 = (const float*)d_in[3];
    const float* b0 = (const float*)d_in[4];
    const float* W1 = (const float*)d_in[5];
    const float* b1 = (const float*)d_in[6];
    const float* W2 = (const float*)d_in[7];
    const float* b2 = (const float*)d_in[8];
    const float* W3 = (const float*)d_in[9];
    const float* b3 = (const float*)d_in[10];
    const float* W4 = (const float*)d_in[11];
    const float* b4 = (const float*)d_in[12];
    float* out = (float*)d_out;
    unsigned short* wsf = (unsigned short*)d_ws;

    const int n = in_sizes[0];

    // 1) convert weights to f16 fragments in workspace (every call)
    prep_w_frags<<<256, 256, 0, stream>>>(W1, W2, W3, W4, wsf);

    // 2) fused PINN-PDE kernel (transposed MFMA, pure f16, reg own-kc)
    const int grid = (n + 15) / 16;
    pinn_mfma_kernel<<<grid, 256, 0, stream>>>(
        x, y, t, W0, b0, b1, b2, b3, b4, wsf, out, n);
}

// Round 16
// 207.302 us; speedup vs baseline: 3.1211x; 3.1211x over previous
//
#include <hip/hip_runtime.h>
#include <cmath>

typedef __attribute__((ext_vector_type(8))) _Float16 f16x8;
typedef __attribute__((ext_vector_type(2))) __fp16 fp16x2;   // cvt_pkrtz return type
typedef __attribute__((ext_vector_type(4))) float f32x4;
typedef unsigned int u32;

__device__ __forceinline__ float tanh_fast(float z) {
    // tanh(z) = 1 - 2/(exp(2z)+1), exp via hardware exp2
    float e = __builtin_amdgcn_exp2f(z * 2.8853900817779268f); // 2*log2(e)
    return 1.0f - 2.0f * __builtin_amdgcn_rcpf(e + 1.0f);
}

__device__ __forceinline__ float f4c(const float4& v, int i) {
    switch (i) { case 0: return v.x; case 1: return v.y; case 2: return v.z; default: return v.w; }
}

// f32 pair -> packed f16x2 in a u32 (RTZ; precision headroom is ample)
__device__ __forceinline__ u32 pk16(float a, float b) {
    fp16x2 hp = __builtin_amdgcn_cvt_pkrtz(a, b);
    return __builtin_bit_cast(u32, hp);
}

// ---------------------------------------------------------------------------
// Prep kernel: convert W1..W4 to f16 (RNE) in MFMA-fragment lane order.
// Layout function (same for A and B operands, HW-verified R4/R6/R8):
//   lane = ((k>>2)&3)*16 + (j&15) ;  s = ((k>>4)&1)*4 + (k&3)
//   blob short-index: (((l*8 + n)*4 + kc)*512 + lane*8 + s
//   l = 0..2 -> W1..W3 (n = j>>4, 8 tiles), l = 3 -> W4 padded to 16 cols, n=0
// ---------------------------------------------------------------------------
__global__ void prep_w_frags(const float* __restrict__ W1, const float* __restrict__ W2,
                             const float* __restrict__ W3, const float* __restrict__ W4,
                             unsigned short* __restrict__ wsf)
{
    int t = blockIdx.x * blockDim.x + threadIdx.x;   // 0 .. 65535
    int l = t >> 14;
    int rem = t & 16383;
    int k = rem >> 7;
    int j = rem & 127;
    float f;
    if (l == 0)      f = W1[k*128 + j];
    else if (l == 1) f = W2[k*128 + j];
    else if (l == 2) f = W3[k*128 + j];
    else {
        if (j >= 16) return;
        f = (j < 4) ? W4[k*4 + j] : 0.0f;
    }
    _Float16 hf = (_Float16)f;                       // RNE
    unsigned short h16 = __builtin_bit_cast(unsigned short, hf);
    int n = j >> 4, jm = j & 15;
    int kc = k >> 5, half = (k >> 4) & 1, qk = (k >> 2) & 3, e = k & 3;
    int lane = qk*16 + jm, s = half*4 + e;
    size_t idx = (((size_t)l*8 + n)*4 + kc)*512 + (size_t)lane*8 + s;
    wsf[idx] = h16;
}

// ---------------------------------------------------------------------------
// Main kernel (transposed, pure f16 single-pass): 16 points/WG, 4 waves.
// Z^T = W^T * S :  A = f16 weight fragments from wsf (global, L2-hot),
//                  B = f16 state fragments; kc==wv comes from the wave's own
//                  registers (it wrote them), kc!=wv from LDS.
// LDS 28 KB.  launch_bounds(256,4): 128 VGPR/wave budget -- (256,5) starved
// the unified VGPR/AGPR file and spilled 2.8 GB/dispatch to scratch (R15).
// ---------------------------------------------------------------------------
__global__ __launch_bounds__(256, 4)
void pinn_mfma_kernel(
    const float* __restrict__ gx, const float* __restrict__ gy, const float* __restrict__ gt,
    const float* __restrict__ W0, const float* __restrict__ b0,
    const float* __restrict__ b1, const float* __restrict__ b2, const float* __restrict__ b3,
    const float* __restrict__ b4,
    const unsigned short* __restrict__ wsf,
    float* __restrict__ out, int n)
{
    __shared__ uint4 Sfh[4][7][64];       // state fragments : 28672 B

    const int tid  = threadIdx.x;
    const int lane = tid & 63;
    const int wv   = tid >> 6;            // wave 0..3 -> owns kc=wv
    const int q    = lane >> 4;           // 0..3
    const int jm   = lane & 15;           // point index p
    const int gp0  = blockIdx.x * 16;

    auto wfrag = [&](int l, int mt, int kc) -> f16x8 {
        return *reinterpret_cast<const f16x8*>(
            wsf + (((size_t)l*8 + mt)*4 + kc)*512 + (size_t)lane*8);
    };

    // ---- point coords (one point per 16-lane group) ----
    int gp = gp0 + jm; if (gp >= n) gp = n - 1;
    const float xv = gx[gp], yv = gy[gp], tv = gt[gp];

    // ---- W0 rows + all biases for owned j's: j = (2wv+ms)*16 + q*4 + i ----
    const int j0a = (2*wv + 0)*16 + q*4;
    const int j0b = (2*wv + 1)*16 + q*4;
    float4 w0x[2], w0y[2], w0t[2], b0v[2], bias[3][2];
    w0x[0] = *reinterpret_cast<const float4*>(W0 + j0a);
    w0x[1] = *reinterpret_cast<const float4*>(W0 + j0b);
    w0y[0] = *reinterpret_cast<const float4*>(W0 + 128 + j0a);
    w0y[1] = *reinterpret_cast<const float4*>(W0 + 128 + j0b);
    w0t[0] = *reinterpret_cast<const float4*>(W0 + 256 + j0a);
    w0t[1] = *reinterpret_cast<const float4*>(W0 + 256 + j0b);
    b0v[0] = *reinterpret_cast<const float4*>(b0 + j0a);
    b0v[1] = *reinterpret_cast<const float4*>(b0 + j0b);
    bias[0][0] = *reinterpret_cast<const float4*>(b1 + j0a);
    bias[0][1] = *reinterpret_cast<const float4*>(b1 + j0b);
    bias[1][0] = *reinterpret_cast<const float4*>(b2 + j0a);
    bias[1][1] = *reinterpret_cast<const float4*>(b2 + j0b);
    bias[2][0] = *reinterpret_cast<const float4*>(b3 + j0a);
    bias[2][1] = *reinterpret_cast<const float4*>(b3 + j0b);

    // ---- pack-and-store helper state (packed f16 cvt) ----
    u32 hw[7][4];
    float tmp[7];
    auto pack7 = [&](int sidx, const float* o) {
        if ((sidx & 1) == 0) {
            #pragma unroll
            for (int v = 0; v < 7; ++v) tmp[v] = o[v];
        } else {
            const int d = sidx >> 1;
            #pragma unroll
            for (int v = 0; v < 7; ++v)
                hw[v][d] = pk16(tmp[v], o[v]);
        }
    };
    auto storeFrags = [&]() {
        #pragma unroll
        for (int v = 0; v < 7; ++v)
            Sfh[wv][v][lane] = make_uint4(hw[v][0], hw[v][1], hw[v][2], hw[v][3]);
    };
    auto ownFrag = [&](int v) -> f16x8 {
        return __builtin_bit_cast(f16x8, make_uint4(hw[v][0], hw[v][1], hw[v][2], hw[v][3]));
    };

    // ---- layer 0: 3 -> 128, seed value + 6 derivative vectors ----
    #pragma unroll
    for (int ms = 0; ms < 2; ++ms) {
        #pragma unroll
        for (int i = 0; i < 4; ++i) {
            const float wx = f4c(w0x[ms], i), wy = f4c(w0y[ms], i), wt = f4c(w0t[ms], i);
            float z = fmaf(xv, wx, fmaf(yv, wy, fmaf(tv, wt, f4c(b0v[ms], i))));
            float s = tanh_fast(z);
            float d = 1.0f - s*s;
            float m2sd = -2.0f * s * d;
            float o[7] = { s, d*wx, d*wy, d*wt, m2sd*wx*wx, m2sd*wy*wy, m2sd*wx*wy };
            pack7(ms*4 + i, o);
        }
    }
    storeFrags();
    __syncthreads();

    // ---- hidden layers 1..3 via MFMA (f16), transposed ----
    #pragma unroll
    for (int l = 0; l < 3; ++l) {
        // this layer's weight fragments (A-operands)
        f16x8 wf[2][4];   // [ms][kc]
        #pragma unroll
        for (int ms = 0; ms < 2; ++ms)
          #pragma unroll
          for (int kc = 0; kc < 4; ++kc)
            wf[ms][kc] = wfrag(l, 2*wv + ms, kc);

        f32x4 acc[7][2];
        #pragma unroll
        for (int v = 0; v < 7; ++v)
          #pragma unroll
          for (int ms = 0; ms < 2; ++ms)
            acc[v][ms] = (f32x4){0.f, 0.f, 0.f, 0.f};

        #pragma unroll
        for (int kc = 0; kc < 4; ++kc) {
          #pragma unroll
          for (int v = 0; v < 7; ++v) {
            f16x8 bh = (kc == wv) ? ownFrag(v)
                                  : *reinterpret_cast<const f16x8*>(&Sfh[kc][v][lane]);
            #pragma unroll
            for (int ms = 0; ms < 2; ++ms)
                acc[v][ms] = __builtin_amdgcn_mfma_f32_16x16x32_f16(wf[ms][kc], bh, acc[v][ms], 0, 0, 0);
          }
        }
        __syncthreads();   // all reads of Sfh done before overwrite

        // in-register nonlinearity + derivative propagation + repack
        #pragma unroll
        for (int ms = 0; ms < 2; ++ms) {
            #pragma unroll
            for (int i = 0; i < 4; ++i) {
                float z   = acc[0][ms][i] + f4c(bias[l][ms], i);
                float zx  = acc[1][ms][i];
                float zy  = acc[2][ms][i];
                float zt  = acc[3][ms][i];
                float zxx = acc[4][ms][i];
                float zyy = acc[5][ms][i];
                float zxy = acc[6][ms][i];
                float s = tanh_fast(z);
                float d = 1.0f - s*s;
                float m2s = -2.0f * s;
                float o[7] = { s, d*zx, d*zy, d*zt,
                               d * fmaf(m2s * zx, zx, zxx),
                               d * fmaf(m2s * zy, zy, zyy),
                               d * fmaf(m2s * zx, zy, zxy) };
                pack7(ms*4 + i, o);
            }
        }
        storeFrags();
        __syncthreads();
    }

    // ---- final layer 128 -> 4 (wave 0 only; A = W4^T padded to 16 rows) ----
    if (wv == 0) {
        f16x8 w4[4];
        #pragma unroll
        for (int kc = 0; kc < 4; ++kc)
            w4[kc] = wfrag(3, 0, kc);

        f32x4 a4[7];
        #pragma unroll
        for (int v = 0; v < 7; ++v) a4[v] = (f32x4){0.f, 0.f, 0.f, 0.f};

        #pragma unroll
        for (int kc = 0; kc < 4; ++kc)
          #pragma unroll
          for (int v = 0; v < 7; ++v) {
            f16x8 bh = (kc == 0) ? ownFrag(v)
                                 : *reinterpret_cast<const f16x8*>(&Sfh[kc][v][lane]);
            a4[v] = __builtin_amdgcn_mfma_f32_16x16x32_f16(w4[kc], bh, a4[v], 0, 0, 0);
          }

        // lanes with q==0 hold outputs o = 0..3 for point jm in a4[v][o]
        if (q == 0) {
            float r[7][4];
            #pragma unroll
            for (int v = 0; v < 7; ++v) {
                r[v][0] = a4[v][0]; r[v][1] = a4[v][1];
                r[v][2] = a4[v][2]; r[v][3] = a4[v][3];
            }
            const float u  = r[0][0] + b4[0];
            const float v  = r[0][1] + b4[1];
            const float a  = r[0][3] + b4[3];
            const float u_x = r[1][0], u_y = r[2][0], u_t = r[3][0];
            const float v_x = r[1][1], v_y = r[2][1], v_t = r[3][1];
            const float p_x = r[1][2], p_y = r[2][2];
            const float a_x = r[1][3], a_y = r[2][3], a_t = r[3][3];
            const float u_xx = r[4][0], u_yy = r[5][0];
            const float v_xx = r[4][1], v_yy = r[5][1];
            const float a_xx = r[4][3], a_yy = r[5][3], a_xy = r[6][3];

            const float MU1 = 0.001f, MU2 = 1.8e-5f;
            const float RHO1 = 1000.0f, RHO2 = 1.225f;
            const float SIGMA = 0.0728f, GACC = 9.81f;

            const float mu   = MU2 + (MU1 - MU2) * a;
            const float mu_x = (MU1 - MU2) * a_x;
            const float mu_y = (MU1 - MU2) * a_y;
            const float rho  = RHO2 + (RHO1 - RHO2) * a;

            const float abs_grad = sqrtf(a_x*a_x + a_y*a_y + 1e-12f);
            const float ag3 = abs_grad * abs_grad * abs_grad;
            const float curvature =
                -((a_xx + a_yy) / abs_grad
                  - (a_x*a_x*a_xx + a_y*a_y*a_yy + 2.0f*a_x*a_y*a_xy) / ag3);

            const float one_Re   = mu   / RHO2;
            const float one_Re_x = mu_x / RHO2;
            const float one_Re_y = mu_y / RHO2;
            const float one_We   = SIGMA / RHO2;
            const float one_Fr   = GACC;
            const float rr       = rho / RHO2;

            const float PDE_m = u_x + v_y;
            const float PDE_a = a_t + u*a_x + v*a_y;
            const float PDE_u = (u_t + u*u_x + v*u_y) * rr + p_x
                                - one_We * curvature * a_x
                                - one_Re * (u_xx + u_yy)
                                - 2.0f * one_Re_x * u_x
                                - one_Re_y * (u_y + v_x);
            const float PDE_v = (v_t + u*v_x + v*v_y) * rr + p_y
                                - one_We * curvature * a_y
                                - rr * one_Fr
                                - one_Re * (v_xx + v_yy)
                                - 2.0f * one_Re_y * v_y
                                - one_Re_x * (u_y + v_x);

            if (gp0 + jm < n) {
                float4 res; res.x = PDE_m; res.y = PDE_u; res.z = PDE_v; res.w = PDE_a;
                *reinterpret_cast<float4*>(out + (size_t)(gp0 + jm) * 4) = res;
            }
        }
    }
}

extern "C" void kernel_launch(void* const* d_in, const int* in_sizes, int n_in,
                              void* d_out, int out_size, void* d_ws, size_t ws_size,
                              hipStream_t stream)
{
    const float* x  = (const float*)d_in[0];
    const float* y  = (const float*)d_in[1];
    const float* t  = (const float*)d_in[2];
    const float* W0 = (const float*)d_in[3];
    const float* b0 = (const float*)d_in[4];
    const float* W1 = (const float*)d_in[5];
    const float* b1 = (const float*)d_in[6];
    const float* W2 = (const float*)d_in[7];
    const float* b2 = (const float*)d_in[8];
    const float* W3 = (const float*)d_in[9];
    const float* b3 = (const float*)d_in[10];
    const float* W4 = (const float*)d_in[11];
    const float* b4 = (const float*)d_in[12];
    float* out = (float*)d_out;
    unsigned short* wsf = (unsigned short*)d_ws;

    const int n = in_sizes[0];

    // 1) convert weights to f16 fragments in workspace (every call)
    prep_w_frags<<<256, 256, 0, stream>>>(W1, W2, W3, W4, wsf);

    // 2) fused PINN-PDE kernel (transposed MFMA, pure f16, reg own-kc)
    const int grid = (n + 15) / 16;
    pinn_mfma_kernel<<<grid, 256, 0, stream>>>(
        x, y, t, W0, b0, b1, b2, b3, b4, wsf, out, n);
}

// Round 17
// 189.374 us; speedup vs baseline: 3.4165x; 1.0947x over previous
//
#include <hip/hip_runtime.h>
#include <cmath>

typedef __attribute__((ext_vector_type(8))) _Float16 f16x8;
typedef __attribute__((ext_vector_type(2))) __fp16 fp16x2;   // cvt_pkrtz return type
typedef __attribute__((ext_vector_type(4))) float f32x4;
typedef unsigned int u32;

__device__ __forceinline__ float tanh_fast(float z) {
    // tanh(z) = 1 - 2/(exp(2z)+1), exp via hardware exp2
    float e = __builtin_amdgcn_exp2f(z * 2.8853900817779268f); // 2*log2(e)
    return 1.0f - 2.0f * __builtin_amdgcn_rcpf(e + 1.0f);
}

__device__ __forceinline__ float f4c(const float4& v, int i) {
    switch (i) { case 0: return v.x; case 1: return v.y; case 2: return v.z; default: return v.w; }
}

// f32 pair -> packed f16x2 in a u32 (RTZ; precision headroom is ample)
__device__ __forceinline__ u32 pk16(float a, float b) {
    fp16x2 hp = __builtin_amdgcn_cvt_pkrtz(a, b);
    return __builtin_bit_cast(u32, hp);
}

// ---------------------------------------------------------------------------
// Prep kernel: convert W1..W4 to f16 (RNE) in MFMA-fragment lane order.
// Layout function (same for A and B operands, HW-verified R4/R6/R8):
//   lane = ((k>>2)&3)*16 + (j&15) ;  s = ((k>>4)&1)*4 + (k&3)
//   blob short-index: (((l*8 + n)*4 + kc)*512 + lane*8 + s
//   l = 0..2 -> W1..W3 (n = j>>4, 8 tiles), l = 3 -> W4 padded to 16 cols, n=0
// ---------------------------------------------------------------------------
__global__ void prep_w_frags(const float* __restrict__ W1, const float* __restrict__ W2,
                             const float* __restrict__ W3, const float* __restrict__ W4,
                             unsigned short* __restrict__ wsf)
{
    int t = blockIdx.x * blockDim.x + threadIdx.x;   // 0 .. 65535
    int l = t >> 14;
    int rem = t & 16383;
    int k = rem >> 7;
    int j = rem & 127;
    float f;
    if (l == 0)      f = W1[k*128 + j];
    else if (l == 1) f = W2[k*128 + j];
    else if (l == 2) f = W3[k*128 + j];
    else {
        if (j >= 16) return;
        f = (j < 4) ? W4[k*4 + j] : 0.0f;
    }
    _Float16 hf = (_Float16)f;                       // RNE
    unsigned short h16 = __builtin_bit_cast(unsigned short, hf);
    int n = j >> 4, jm = j & 15;
    int kc = k >> 5, half = (k >> 4) & 1, qk = (k >> 2) & 3, e = k & 3;
    int lane = qk*16 + jm, s = half*4 + e;
    size_t idx = (((size_t)l*8 + n)*4 + kc)*512 + (size_t)lane*8 + s;
    wsf[idx] = h16;
}

// ---------------------------------------------------------------------------
// Main kernel (transposed, pure f16 single-pass): 16 points/WG, 4 waves.
// Z^T = W^T * S :  A = f16 weight fragments from wsf (global, L2-hot),
//                  B = f16 state fragments in LDS.
// Rotated-kc iteration: wave wv walks kc = (wv+ki)&3; ki==0 (COMPILE-TIME)
// uses the wave's own register copy of its fragment.  R16 showed that a
// RUNTIME (kc==wv) select between registers and LDS forces hw[] to scratch
// (238 MB/dispatch of spill write-back); the rotation makes the select
// static and keeps hw[] in registers.
// ---------------------------------------------------------------------------
__global__ __launch_bounds__(256, 4)
void pinn_mfma_kernel(
    const float* __restrict__ gx, const float* __restrict__ gy, const float* __restrict__ gt,
    const float* __restrict__ W0, const float* __restrict__ b0,
    const float* __restrict__ b1, const float* __restrict__ b2, const float* __restrict__ b3,
    const float* __restrict__ b4,
    const unsigned short* __restrict__ wsf,
    float* __restrict__ out, int n)
{
    __shared__ uint4 Sfh[4][7][64];       // state fragments : 28672 B

    const int tid  = threadIdx.x;
    const int lane = tid & 63;
    const int wv   = tid >> 6;            // wave 0..3 -> owns kc=wv
    const int q    = lane >> 4;           // 0..3
    const int jm   = lane & 15;           // point index p
    const int gp0  = blockIdx.x * 16;

    auto wfrag = [&](int l, int mt, int kc) -> f16x8 {
        return *reinterpret_cast<const f16x8*>(
            wsf + (((size_t)l*8 + mt)*4 + kc)*512 + (size_t)lane*8);
    };

    // ---- point coords (one point per 16-lane group) ----
    int gp = gp0 + jm; if (gp >= n) gp = n - 1;
    const float xv = gx[gp], yv = gy[gp], tv = gt[gp];

    // ---- W0 rows + all biases for owned j's: j = (2wv+ms)*16 + q*4 + i ----
    const int j0a = (2*wv + 0)*16 + q*4;
    const int j0b = (2*wv + 1)*16 + q*4;
    float4 w0x[2], w0y[2], w0t[2], b0v[2], bias[3][2];
    w0x[0] = *reinterpret_cast<const float4*>(W0 + j0a);
    w0x[1] = *reinterpret_cast<const float4*>(W0 + j0b);
    w0y[0] = *reinterpret_cast<const float4*>(W0 + 128 + j0a);
    w0y[1] = *reinterpret_cast<const float4*>(W0 + 128 + j0b);
    w0t[0] = *reinterpret_cast<const float4*>(W0 + 256 + j0a);
    w0t[1] = *reinterpret_cast<const float4*>(W0 + 256 + j0b);
    b0v[0] = *reinterpret_cast<const float4*>(b0 + j0a);
    b0v[1] = *reinterpret_cast<const float4*>(b0 + j0b);
    bias[0][0] = *reinterpret_cast<const float4*>(b1 + j0a);
    bias[0][1] = *reinterpret_cast<const float4*>(b1 + j0b);
    bias[1][0] = *reinterpret_cast<const float4*>(b2 + j0a);
    bias[1][1] = *reinterpret_cast<const float4*>(b2 + j0b);
    bias[2][0] = *reinterpret_cast<const float4*>(b3 + j0a);
    bias[2][1] = *reinterpret_cast<const float4*>(b3 + j0b);

    // ---- pack-and-store helper state (packed f16 cvt) ----
    u32 hw[7][4];
    float tmp[7];
    auto pack7 = [&](int sidx, const float* o) {
        if ((sidx & 1) == 0) {
            #pragma unroll
            for (int v = 0; v < 7; ++v) tmp[v] = o[v];
        } else {
            const int d = sidx >> 1;
            #pragma unroll
            for (int v = 0; v < 7; ++v)
                hw[v][d] = pk16(tmp[v], o[v]);
        }
    };
    auto storeFrags = [&]() {
        #pragma unroll
        for (int v = 0; v < 7; ++v)
            Sfh[wv][v][lane] = make_uint4(hw[v][0], hw[v][1], hw[v][2], hw[v][3]);
    };
    auto ownFrag = [&](int v) -> f16x8 {
        return __builtin_bit_cast(f16x8, make_uint4(hw[v][0], hw[v][1], hw[v][2], hw[v][3]));
    };

    // ---- layer 0: 3 -> 128, seed value + 6 derivative vectors ----
    #pragma unroll
    for (int ms = 0; ms < 2; ++ms) {
        #pragma unroll
        for (int i = 0; i < 4; ++i) {
            const float wx = f4c(w0x[ms], i), wy = f4c(w0y[ms], i), wt = f4c(w0t[ms], i);
            float z = fmaf(xv, wx, fmaf(yv, wy, fmaf(tv, wt, f4c(b0v[ms], i))));
            float s = tanh_fast(z);
            float d = 1.0f - s*s;
            float m2sd = -2.0f * s * d;
            float o[7] = { s, d*wx, d*wy, d*wt, m2sd*wx*wx, m2sd*wy*wy, m2sd*wx*wy };
            pack7(ms*4 + i, o);
        }
    }
    storeFrags();
    __syncthreads();

    // ---- hidden layers 1..3 via MFMA (f16), transposed, rotated kc ----
    #pragma unroll
    for (int l = 0; l < 3; ++l) {
        // weight fragments in rotation order: wfr[ms][ki] = W-tile (2wv+ms, (wv+ki)&3)
        f16x8 wfr[2][4];
        #pragma unroll
        for (int ms = 0; ms < 2; ++ms)
          #pragma unroll
          for (int ki = 0; ki < 4; ++ki)
            wfr[ms][ki] = wfrag(l, 2*wv + ms, (wv + ki) & 3);

        f32x4 acc[7][2];
        #pragma unroll
        for (int v = 0; v < 7; ++v)
          #pragma unroll
          for (int ms = 0; ms < 2; ++ms)
            acc[v][ms] = (f32x4){0.f, 0.f, 0.f, 0.f};

        #pragma unroll
        for (int ki = 0; ki < 4; ++ki) {
          const int kc = (wv + ki) & 3;     // runtime, used ONLY in LDS address
          #pragma unroll
          for (int v = 0; v < 7; ++v) {
            f16x8 bh;
            if (ki == 0) bh = ownFrag(v);   // compile-time branch: register path
            else         bh = *reinterpret_cast<const f16x8*>(&Sfh[kc][v][lane]);
            #pragma unroll
            for (int ms = 0; ms < 2; ++ms)
                acc[v][ms] = __builtin_amdgcn_mfma_f32_16x16x32_f16(wfr[ms][ki], bh, acc[v][ms], 0, 0, 0);
          }
        }
        __syncthreads();   // all reads of Sfh done before overwrite

        // in-register nonlinearity + derivative propagation + repack
        #pragma unroll
        for (int ms = 0; ms < 2; ++ms) {
            #pragma unroll
            for (int i = 0; i < 4; ++i) {
                float z   = acc[0][ms][i] + f4c(bias[l][ms], i);
                float zx  = acc[1][ms][i];
                float zy  = acc[2][ms][i];
                float zt  = acc[3][ms][i];
                float zxx = acc[4][ms][i];
                float zyy = acc[5][ms][i];
                float zxy = acc[6][ms][i];
                float s = tanh_fast(z);
                float d = 1.0f - s*s;
                float m2s = -2.0f * s;
                float o[7] = { s, d*zx, d*zy, d*zt,
                               d * fmaf(m2s * zx, zx, zxx),
                               d * fmaf(m2s * zy, zy, zyy),
                               d * fmaf(m2s * zx, zy, zxy) };
                pack7(ms*4 + i, o);
            }
        }
        storeFrags();
        __syncthreads();
    }

    // ---- final layer 128 -> 4 (wave 0 only; A = W4^T padded to 16 rows) ----
    if (wv == 0) {
        f16x8 w4[4];
        #pragma unroll
        for (int kc = 0; kc < 4; ++kc)
            w4[kc] = wfrag(3, 0, kc);

        f32x4 a4[7];
        #pragma unroll
        for (int v = 0; v < 7; ++v) a4[v] = (f32x4){0.f, 0.f, 0.f, 0.f};

        #pragma unroll
        for (int kc = 0; kc < 4; ++kc)
          #pragma unroll
          for (int v = 0; v < 7; ++v) {
            f16x8 bh;
            if (kc == 0) bh = ownFrag(v);   // wave 0 owns kc=0; branch is compile-time
            else         bh = *reinterpret_cast<const f16x8*>(&Sfh[kc][v][lane]);
            a4[v] = __builtin_amdgcn_mfma_f32_16x16x32_f16(w4[kc], bh, a4[v], 0, 0, 0);
          }

        // lanes with q==0 hold outputs o = 0..3 for point jm in a4[v][o]
        if (q == 0) {
            float r[7][4];
            #pragma unroll
            for (int v = 0; v < 7; ++v) {
                r[v][0] = a4[v][0]; r[v][1] = a4[v][1];
                r[v][2] = a4[v][2]; r[v][3] = a4[v][3];
            }
            const float u  = r[0][0] + b4[0];
            const float v  = r[0][1] + b4[1];
            const float a  = r[0][3] + b4[3];
            const float u_x = r[1][0], u_y = r[2][0], u_t = r[3][0];
            const float v_x = r[1][1], v_y = r[2][1], v_t = r[3][1];
            const float p_x = r[1][2], p_y = r[2][2];
            const float a_x = r[1][3], a_y = r[2][3], a_t = r[3][3];
            const float u_xx = r[4][0], u_yy = r[5][0];
            const float v_xx = r[4][1], v_yy = r[5][1];
            const float a_xx = r[4][3], a_yy = r[5][3], a_xy = r[6][3];

            const float MU1 = 0.001f, MU2 = 1.8e-5f;
            const float RHO1 = 1000.0f, RHO2 = 1.225f;
            const float SIGMA = 0.0728f, GACC = 9.81f;

            const float mu   = MU2 + (MU1 - MU2) * a;
            const float mu_x = (MU1 - MU2) * a_x;
            const float mu_y = (MU1 - MU2) * a_y;
            const float rho  = RHO2 + (RHO1 - RHO2) * a;

            const float abs_grad = sqrtf(a_x*a_x + a_y*a_y + 1e-12f);
            const float ag3 = abs_grad * abs_grad * abs_grad;
            const float curvature =
                -((a_xx + a_yy) / abs_grad
                  - (a_x*a_x*a_xx + a_y*a_y*a_yy + 2.0f*a_x*a_y*a_xy) / ag3);

            const float one_Re   = mu   / RHO2;
            const float one_Re_x = mu_x / RHO2;
            const float one_Re_y = mu_y / RHO2;
            const float one_We   = SIGMA / RHO2;
            const float one_Fr   = GACC;
            const float rr       = rho / RHO2;

            const float PDE_m = u_x + v_y;
            const float PDE_a = a_t + u*a_x + v*a_y;
            const float PDE_u = (u_t + u*u_x + v*u_y) * rr + p_x
                                - one_We * curvature * a_x
                                - one_Re * (u_xx + u_yy)
                                - 2.0f * one_Re_x * u_x
                                - one_Re_y * (u_y + v_x);
            const float PDE_v = (v_t + u*v_x + v*v_y) * rr + p_y
                                - one_We * curvature * a_y
                                - rr * one_Fr
                                - one_Re * (v_xx + v_yy)
                                - 2.0f * one_Re_y * v_y
                                - one_Re_x * (u_y + v_x);

            if (gp0 + jm < n) {
                float4 res; res.x = PDE_m; res.y = PDE_u; res.z = PDE_v; res.w = PDE_a;
                *reinterpret_cast<float4*>(out + (size_t)(gp0 + jm) * 4) = res;
            }
        }
    }
}

extern "C" void kernel_launch(void* const* d_in, const int* in_sizes, int n_in,
                              void* d_out, int out_size, void* d_ws, size_t ws_size,
                              hipStream_t stream)
{
    const float* x  = (const float*)d_in[0];
    const float* y  = (const float*)d_in[1];
    const float* t  = (const float*)d_in[2];
    const float* W0 = (const float*)d_in[3];
    const float* b0 = (const float*)d_in[4];
    const float* W1 = (const float*)d_in[5];
    const float* b1 = (const float*)d_in[6];
    const float* W2 = (const float*)d_in[7];
    const float* b2 = (const float*)d_in[8];
    const float* W3 = (const float*)d_in[9];
    const float* b3 = (const float*)d_in[10];
    const float* W4 = (const float*)d_in[11];
    const float* b4 = (const float*)d_in[12];
    float* out = (float*)d_out;
    unsigned short* wsf = (unsigned short*)d_ws;

    const int n = in_sizes[0];

    // 1) convert weights to f16 fragments in workspace (every call)
    prep_w_frags<<<256, 256, 0, stream>>>(W1, W2, W3, W4, wsf);

    // 2) fused PINN-PDE kernel (transposed MFMA, pure f16, rotated-kc reg reuse)
    const int grid = (n + 15) / 16;
    pinn_mfma_kernel<<<grid, 256, 0, stream>>>(
        x, y, t, W0, b0, b1, b2, b3, b4, wsf, out, n);
}